// Round 3
// baseline (493.009 us; speedup 1.0000x reference)
//
#include <hip/hip_runtime.h>
#include <math.h>

// Capsule dynamic routing, B=64, R=4608, C=32, Din=Dout=16, 3 iters.
// b-logits are linear in v: b after k iters = u_hat . (v1+...+vk), so we keep
// only vsum[B,C,16] and recompute u_hat per pass (never materialized).
//
// Round-3 change: 8 b per thread (8 waves/block instead of 16) -> each W byte
// in LDS is read 8x instead of 16x, halving the LDS-pipe load (the measured
// bottleneck: 9.4M bank-conflict cycles, VALUBusy only 43%). 2 FMA per LDS
// byte. VGPR ~210 -> launch_bounds(512,2).

#define B_    64
#define R_    4608
#define C_    32
#define RB    18
#define NBLK  (R_ / RB)      // 256
#define SELEM 32768          // B_*C_*16

__device__ __forceinline__ void gload_lds16(const void* g, void* l) {
    __builtin_amdgcn_global_load_lds(
        (const __attribute__((address_space(1))) void*)g,
        (__attribute__((address_space(3))) void*)l, 16, 0, 0);
}

template<bool FIRST, bool ATOMIC>
__global__ __launch_bounds__(512, 2)
void caps_pass(const float* __restrict__ x, const float* __restrict__ W,
               const float* __restrict__ vsumg, float* __restrict__ sdst)
{
    __shared__ float wlds[2][8192];          // 2 x 32 KB W tiles
    const int tid  = threadIdx.x;
    const int lane = tid & 63;
    const int c    = tid & 31;
    const int dh   = (tid >> 5) & 1;
    const int w    = tid >> 6;               // wave 0..7
    const int r0   = blockIdx.x * RB;
    const int b0   = w << 3;                 // 8 b per wave

    // byte-level XOR swizzle key for this thread's W reads
    const int key = (c & 7) << 4;
    const int cb  = (c << 10) + (dh << 5);   // byte base within W tile (i=0,j=0)

    float sacc[8][8];
#pragma unroll
    for (int q = 0; q < 8; ++q)
#pragma unroll
        for (int k = 0; k < 8; ++k) sacc[q][k] = 0.0f;

    float vreg[8][8];
    if (!FIRST) {
#pragma unroll
        for (int q = 0; q < 8; ++q) {
            const float4* vp = (const float4*)(vsumg + ((((b0 + q) << 5) + c) << 4) + (dh << 3));
            float4 a0 = vp[0], a1 = vp[1];
            vreg[q][0] = a0.x; vreg[q][1] = a0.y; vreg[q][2] = a0.z; vreg[q][3] = a0.w;
            vreg[q][4] = a1.x; vreg[q][5] = a1.y; vreg[q][6] = a1.z; vreg[q][7] = a1.w;
        }
    }

    // staging: wave w stages tile bytes [w*4096, w*4096+4096) as 4 chunks.
    // LDS[D] = W[D ^ ((D>>10 & 7)<<4)] -> pre-swizzle the *global* source.
    // For chunk (w,j): key = ((w*4+j)&7)<<4, uniform per instruction.
#define STAGE(buf, r)                                                               \
    do {                                                                            \
        const char* wr_ = (const char*)W + ((size_t)(r) << 15);                     \
        _Pragma("unroll")                                                           \
        for (int j_ = 0; j_ < 4; ++j_) {                                            \
            const int D_ = (w << 12) + (j_ << 10);                                  \
            const int k_ = (((w << 2) + j_) & 7) << 4;                              \
            gload_lds16(wr_ + ((D_ + (lane << 4)) ^ k_), (char*)wlds[buf] + D_);    \
        }                                                                           \
    } while (0)

    // x rows for this wave are uniform -> scalar loads
    const int wu = __builtin_amdgcn_readfirstlane(w);
    const float* xw = x + (size_t)((wu << 3) * R_ + r0) * 16;

    STAGE(0, r0);

#pragma unroll 1
    for (int t = 0; t < RB; ++t) {
        const int cur = t & 1;
        if (t + 1 < RB) {
            STAGE(cur ^ 1, r0 + t + 1);
            asm volatile("s_waitcnt vmcnt(4)" ::: "memory");
        } else {
            asm volatile("s_waitcnt vmcnt(0)" ::: "memory");
        }
        __builtin_amdgcn_s_barrier();
        __builtin_amdgcn_sched_barrier(0);

        const char* lb = (const char*)wlds[cur];
        const float* xr = xw + t * 16;

        float u[8][8];
#pragma unroll
        for (int q = 0; q < 8; ++q)
#pragma unroll
            for (int k = 0; k < 8; ++k) u[q][k] = 0.0f;

#pragma unroll
        for (int i4 = 0; i4 < 4; ++i4) {
            // x[b, r, i4*4 .. i4*4+3] for all 8 b of this wave (scalar loads)
            float4 xq[8];
#pragma unroll
            for (int q = 0; q < 8; ++q)
                xq[q] = *(const float4*)(xr + (size_t)q * (R_ * 16) + (i4 << 2));

#pragma unroll
            for (int j = 0; j < 4; ++j) {
                const int i = (i4 << 2) + j;
                const int A = (cb + (i << 6)) ^ key;
                float4 w0 = *(const float4*)(lb + A);
                float4 w1 = *(const float4*)(lb + (A ^ 16));
                float wv[8] = {w0.x, w0.y, w0.z, w0.w, w1.x, w1.y, w1.z, w1.w};
#pragma unroll
                for (int q = 0; q < 8; ++q) {
                    const float xv = (j == 0) ? xq[q].x : (j == 1) ? xq[q].y
                                   : (j == 2) ? xq[q].z : xq[q].w;
#pragma unroll
                    for (int k = 0; k < 8; ++k)
                        u[q][k] = fmaf(xv, wv[k], u[q][k]);
                }
            }
        }

#pragma unroll
        for (int q = 0; q < 8; ++q) {
            float cij;
            if (FIRST) {
                cij = 0.03125f;
            } else {
                float th = 0.0f;
#pragma unroll
                for (int k = 0; k < 8; ++k) th = fmaf(u[q][k], vreg[q][k], th);
                th += __shfl_xor(th, 32);          // fold the two d-halves
                float m = th;
#pragma unroll
                for (int off = 16; off >= 1; off >>= 1)
                    m = fmaxf(m, __shfl_xor(m, off));
                const float e = __expf(th - m);
                float ssum = e;
#pragma unroll
                for (int off = 16; off >= 1; off >>= 1)
                    ssum += __shfl_xor(ssum, off);
                cij = e / ssum;
            }
#pragma unroll
            for (int k = 0; k < 8; ++k)
                sacc[q][k] = fmaf(cij, u[q][k], sacc[q][k]);
        }

        __builtin_amdgcn_s_barrier();
    }
#undef STAGE

    if (ATOMIC) {
#pragma unroll
        for (int q = 0; q < 8; ++q) {
            float* sp = sdst + ((((b0 + q) << 5) + c) << 4) + (dh << 3);
#pragma unroll
            for (int k = 0; k < 8; ++k) atomicAdd(sp + k, sacc[q][k]);
        }
    } else {
#pragma unroll
        for (int q = 0; q < 8; ++q) {
            float* sp = sdst + ((size_t)blockIdx.x << 15) + ((((b0 + q) << 5) + c) << 4) + (dh << 3);
            ((float4*)sp)[0] = make_float4(sacc[q][0], sacc[q][1], sacc[q][2], sacc[q][3]);
            ((float4*)sp)[1] = make_float4(sacc[q][4], sacc[q][5], sacc[q][6], sacc[q][7]);
        }
    }
}

// stage-1 tree reduce: grid (128, 8) x 256. Block (e-chunk, pg) sums partials
// p in [pg*32, pg*32+32) for 256 consecutive elements -> s2[pg][e].
__global__ __launch_bounds__(256)
void caps_reduce1(const float* __restrict__ sp, float* __restrict__ s2)
{
    const int e  = blockIdx.x * 256 + threadIdx.x;   // 0..32767
    const int pg = blockIdx.y;
    const float* p0 = sp + (size_t)pg * 32 * SELEM + e;
    float a = 0.0f;
#pragma unroll 8
    for (int p = 0; p < 32; ++p) a += p0[(size_t)p * SELEM];
    s2[pg * SELEM + e] = a;
}

// stage-2 reduce + squash. mode 0: vsum = v; 1: vsum += v; 2: out = v.
__global__ __launch_bounds__(256)
void caps_reduce2(const float* __restrict__ src, int P,
                  float* __restrict__ vsum, float* __restrict__ out, int mode)
{
    const int e = blockIdx.x * 256 + threadIdx.x;    // 0..32767
    float a = 0.0f;
    for (int p = 0; p < P; ++p) a += src[(size_t)p * SELEM + e];
    float sq = a * a;
#pragma unroll
    for (int off = 8; off >= 1; off >>= 1) sq += __shfl_xor(sq, off);
    const float n = sqrtf(sq);
    const float v = a * (sq / (1.0f + sq) / (n + 1e-8f));
    if (mode == 0)      vsum[e] = v;
    else if (mode == 1) vsum[e] += v;
    else                out[e] = v;
}

extern "C" void kernel_launch(void* const* d_in, const int* in_sizes, int n_in,
                              void* d_out, int out_size, void* d_ws, size_t ws_size,
                              hipStream_t stream)
{
    const float* x = (const float*)d_in[0];          // [64, 4608, 16]
    const float* W = (const float*)d_in[1];          // [4608, 32, 16, 16]
    float* out = (float*)d_out;                      // [64, 32, 16]

    const size_t PART_BYTES = (size_t)(NBLK + 8 + 1) * SELEM * sizeof(float); // ~33.1 MiB
    if (ws_size >= PART_BYTES) {
        float* s_part = (float*)d_ws;                // [256][32768]
        float* s2     = s_part + (size_t)NBLK * SELEM;  // [8][32768]
        float* vsum   = s2 + (size_t)8 * SELEM;         // [32768]

        caps_pass<true, false><<<NBLK, 512, 0, stream>>>(x, W, nullptr, s_part);
        caps_reduce1<<<dim3(128, 8), 256, 0, stream>>>(s_part, s2);
        caps_reduce2<<<128, 256, 0, stream>>>(s2, 8, vsum, nullptr, 0);

        caps_pass<false, false><<<NBLK, 512, 0, stream>>>(x, W, vsum, s_part);
        caps_reduce1<<<dim3(128, 8), 256, 0, stream>>>(s_part, s2);
        caps_reduce2<<<128, 256, 0, stream>>>(s2, 8, vsum, nullptr, 1);

        caps_pass<false, false><<<NBLK, 512, 0, stream>>>(x, W, vsum, s_part);
        caps_reduce1<<<dim3(128, 8), 256, 0, stream>>>(s_part, s2);
        caps_reduce2<<<128, 256, 0, stream>>>(s2, 8, nullptr, out, 2);
    } else {
        // fallback: atomic accumulation (well within the validation threshold)
        float* s    = (float*)d_ws;                  // [32768]
        float* vsum = s + SELEM;                     // [32768]

        hipMemsetAsync(s, 0, SELEM * sizeof(float), stream);
        caps_pass<true, true><<<NBLK, 512, 0, stream>>>(x, W, nullptr, s);
        caps_reduce2<<<128, 256, 0, stream>>>(s, 1, vsum, nullptr, 0);

        hipMemsetAsync(s, 0, SELEM * sizeof(float), stream);
        caps_pass<false, true><<<NBLK, 512, 0, stream>>>(x, W, vsum, s);
        caps_reduce2<<<128, 256, 0, stream>>>(s, 1, vsum, nullptr, 1);

        hipMemsetAsync(s, 0, SELEM * sizeof(float), stream);
        caps_pass<false, true><<<NBLK, 512, 0, stream>>>(x, W, vsum, s);
        caps_reduce2<<<128, 256, 0, stream>>>(s, 1, nullptr, out, 2);
    }
}

// Round 4
// 294.501 us; speedup vs baseline: 1.6740x; 1.6740x over previous
//
#include <hip/hip_runtime.h>
#include <math.h>

// Capsule dynamic routing, B=64, R=4608, C=32, Din=Dout=16, 3 iters.
// b-logits are linear in v: b after k iters = u_hat.(v1+...+vk) -> keep only
// vsum[B,C,16]; u_hat recomputed per pass via MFMA (never materialized).
//
// Round-4: einsum moved to matrix cores. mfma_f32_32x32x16_f16: K=16==Din.
// Per r: u[64,512] = X_r[64,16] @ W_r[16,512] = 2 MFMA per wave (16 waves,
// wave w owns N-tile w = cols 32w..32w+31 = capsules {2w,2w+1}, both M-tiles).
// Pass 1 (c_ij=1/32) is a pure GEMM accumulated in the MFMA C operand, and
// fuses the one-time f32->f16 conversion of W into fragment-order wp (ws) and
// x into xb (ws). Passes 2-3: per-r logit o-reduce via 15-shfl reduce-scatter
// (all-static indexing), softmax over c through padded LDS [32][68]
// (conflict-free), c_ij readback as aligned ds_read_b128 (2-way = free).

#define B_    64
#define R_    4608
#define C_    32
#define RB    18
#define NBLK  (R_ / RB)      // 256
#define SELEM 32768          // B_*C_*16

typedef _Float16 half8  __attribute__((ext_vector_type(8)));
typedef _Float16 half2v __attribute__((ext_vector_type(2)));
typedef float    f32x16 __attribute__((ext_vector_type(16)));
typedef float    f32x4v __attribute__((ext_vector_type(4)));

// ---------------------------------------------------------------- MFMA pass
// C/D layout (m74/m101): col = lane&31, row = (reg&3)+8*(reg>>2)+4*(lane>>5).
// A: lane holds A[row=lane&31][k=8*(lane>>5)+e]; B: B[k=8*(lane>>5)+e][col=lane&31].
template<bool FIRST, bool ATOMIC>
__global__ __launch_bounds__(1024, 4)
void caps_mfma(const float* __restrict__ x, const float* __restrict__ W,
               _Float16* __restrict__ xb, _Float16* __restrict__ wp,
               const float* __restrict__ vsumg, float* __restrict__ sdst)
{
    __shared__ float t_lds[32][68];   // [c][b], padded: stride 68 kills conflicts
    __shared__ float c_lds[32][68];

    const int tid  = threadIdx.x;
    const int lane = tid & 63;
    const int w    = tid >> 6;        // 0..15  (N-tile)
    const int h    = lane >> 5;       // k-half / row-half
    const int l31  = lane & 31;
    const int colg = 32*w + l31;      // global col = c*16 + o
    const int c0   = colg >> 4;       // this lane's capsule c
    const int r0   = blockIdx.x * RB;

    f32x16 sacc0, sacc1, zf;
#pragma unroll
    for (int k = 0; k < 16; ++k) { sacc0[k] = 0.f; sacc1[k] = 0.f; zf[k] = 0.f; }

    // vsum fragments, f16-packed (16 VGPRs): vh[mt][e2] = {v(e=2e2), v(e=2e2+1)}
    half2v vh[2][8];
    if (!FIRST) {
#pragma unroll
        for (int mt = 0; mt < 2; ++mt)
#pragma unroll
        for (int e2 = 0; e2 < 8; ++e2) {
            const int eA = 2*e2, eB = 2*e2 + 1;
            const int bA = mt*32 + (eA&3) + 8*(eA>>2) + 4*h;
            const int bB = mt*32 + (eB&3) + 8*(eB>>2) + 4*h;
            half2v t;
            t[0] = (_Float16)vsumg[bA*512 + colg];
            t[1] = (_Float16)vsumg[bB*512 + colg];
            vh[mt][e2] = t;
        }
    }

    const _Float16* xb0 = xb + ((size_t)l31*R_ + r0)*16 + 8*h;
    const _Float16* xb1 = xb0 + (size_t)32*R_*16;
    const _Float16* wpr = wp + (((size_t)r0*16 + w)*64 + lane)*8;
    const int cW = 2*w + (l31 >> 4);
    const int oW = l31 & 15;

    half8 a0c, a1c, bc;               // current fragments (prefetched)
    if (!FIRST) {
        a0c = *(const half8*)xb0;  xb0 += 16;
        a1c = *(const half8*)xb1;  xb1 += 16;
        bc  = *(const half8*)wpr;  wpr += (size_t)16*64*8;
    }

#pragma unroll 1
    for (int t_ = 0; t_ < RB; ++t_) {
        const int r = r0 + t_;

        if (FIRST) {
            // gather W f32 (stride 64B), convert, stash fragment-order f16
            half8 bfrag, a0, a1;
            const float* wsrc = W + (((size_t)r*32 + cW)*16 + 8*h)*16 + oW;
#pragma unroll
            for (int e = 0; e < 8; ++e) bfrag[e] = (_Float16)wsrc[e*16];
            *(half8*)(wp + (((size_t)r*16 + w)*64 + lane)*8) = bfrag;

            const float4* xs0 = (const float4*)(x + ((size_t)l31*R_ + r)*16 + 8*h);
            const float4* xs1 = (const float4*)(x + ((size_t)(32+l31)*R_ + r)*16 + 8*h);
            float4 A0 = xs0[0], B0 = xs0[1], A1 = xs1[0], B1 = xs1[1];
            a0[0]=(_Float16)A0.x; a0[1]=(_Float16)A0.y; a0[2]=(_Float16)A0.z; a0[3]=(_Float16)A0.w;
            a0[4]=(_Float16)B0.x; a0[5]=(_Float16)B0.y; a0[6]=(_Float16)B0.z; a0[7]=(_Float16)B0.w;
            a1[0]=(_Float16)A1.x; a1[1]=(_Float16)A1.y; a1[2]=(_Float16)A1.z; a1[3]=(_Float16)A1.w;
            a1[4]=(_Float16)B1.x; a1[5]=(_Float16)B1.y; a1[6]=(_Float16)B1.z; a1[7]=(_Float16)B1.w;
            if (w == 0) {
                *(half8*)(xb + ((size_t)l31*R_ + r)*16 + 8*h)      = a0;
                *(half8*)(xb + ((size_t)(32+l31)*R_ + r)*16 + 8*h) = a1;
            }
            sacc0 = __builtin_amdgcn_mfma_f32_32x32x16_f16(a0, bfrag, sacc0, 0, 0, 0);
            sacc1 = __builtin_amdgcn_mfma_f32_32x32x16_f16(a1, bfrag, sacc1, 0, 0, 0);
            continue;
        }

        // ---- non-FIRST: u for this r ----
        const f32x16 u0 = __builtin_amdgcn_mfma_f32_32x32x16_f16(a0c, bc, zf, 0, 0, 0);
        const f32x16 u1 = __builtin_amdgcn_mfma_f32_32x32x16_f16(a1c, bc, zf, 0, 0, 0);

        // prefetch next r's fragments (latency hides under the phases below;
        // final iteration reads 16B past range -> lands in adjacent ws, unused)
        a0c = *(const half8*)xb0;  xb0 += 16;
        a1c = *(const half8*)xb1;  xb1 += 16;
        bc  = *(const half8*)wpr;  wpr += (size_t)16*64*8;

        // ---- phase 1: logits t[b][c] = sum_o u*v, reduce-scatter over the 16
        // o-lanes; all private indices compile-time (rule #20) ----
        float tv0 = 0.f, tv1 = 0.f;
#pragma unroll
        for (int mt = 0; mt < 2; ++mt) {
            const f32x16& u = mt ? u1 : u0;
            float p[16];
#pragma unroll
            for (int e2 = 0; e2 < 8; ++e2) {
                p[2*e2]   = u[2*e2]   * (float)vh[mt][e2][0];
                p[2*e2+1] = u[2*e2+1] * (float)vh[mt][e2][1];
            }
            float q8[8];
#pragma unroll
            for (int j = 0; j < 8; ++j) {
                const float aa = p[j], bb = p[8+j];
                const float keep = (lane & 1) ? bb : aa;
                const float send = (lane & 1) ? aa : bb;
                q8[j] = keep + __shfl_xor(send, 1);
            }
            float q4[4];
#pragma unroll
            for (int j = 0; j < 4; ++j) {
                const float aa = q8[j], bb = q8[4+j];
                const float keep = (lane & 2) ? bb : aa;
                const float send = (lane & 2) ? aa : bb;
                q4[j] = keep + __shfl_xor(send, 2);
            }
            float q2[2];
#pragma unroll
            for (int j = 0; j < 2; ++j) {
                const float aa = q4[j], bb = q4[2+j];
                const float keep = (lane & 4) ? bb : aa;
                const float send = (lane & 4) ? aa : bb;
                q2[j] = keep + __shfl_xor(send, 4);
            }
            {
                const float aa = q2[0], bb = q2[1];
                const float keep = (lane & 8) ? bb : aa;
                const float send = (lane & 8) ? aa : bb;
                const float tvm = keep + __shfl_xor(send, 8);
                if (mt == 0) tv0 = tvm; else tv1 = tvm;
            }
        }
        {   // lane holds t of row es = bitrev4(lane&15)
            const int es  = ((lane&1)<<3) | ((lane&2)<<1) | ((lane&4)>>1) | ((lane&8)>>3);
            const int bb0 = (es&3) + 8*(es>>2) + 4*h;
            t_lds[c0][bb0]      = tv0;
            t_lds[c0][32 + bb0] = tv1;
        }
        __syncthreads();

        // ---- phase 2: softmax over c (thread -> (b, c-pair)) ----
        {
            const int a_ = lane & 15;
            const int b2 = 4*w + (lane >> 4);
            const float tA = t_lds[2*a_][b2];
            const float tB = t_lds[2*a_+1][b2];
            float m = fmaxf(tA, tB);
            m = fmaxf(m, __shfl_xor(m, 1));
            m = fmaxf(m, __shfl_xor(m, 2));
            m = fmaxf(m, __shfl_xor(m, 4));
            m = fmaxf(m, __shfl_xor(m, 8));
            const float eA = __expf(tA - m);
            const float eB = __expf(tB - m);
            float zs = eA + eB;
            zs += __shfl_xor(zs, 1);
            zs += __shfl_xor(zs, 2);
            zs += __shfl_xor(zs, 4);
            zs += __shfl_xor(zs, 8);
            const float inv = 1.0f / zs;
            c_lds[2*a_][b2]   = eA * inv;
            c_lds[2*a_+1][b2] = eB * inv;
        }
        __syncthreads();

        // ---- phase 3: sacc += c_ij * u (aligned b128 chunk reads, 2-way=free)
#pragma unroll
        for (int mt = 0; mt < 2; ++mt) {
            const f32x16& u = mt ? u1 : u0;
            f32x16& sa = mt ? sacc1 : sacc0;
            const float* cp = &c_lds[c0][mt*32 + 4*h];
#pragma unroll
            for (int j = 0; j < 4; ++j) {
                const f32x4v ch = *(const f32x4v*)(cp + 8*j);
#pragma unroll
                for (int qq = 0; qq < 4; ++qq)
                    sa[4*j+qq] += ch[qq] * u[4*j+qq];
            }
        }
    }

    // ---- epilogue ----
    const float scale = FIRST ? 0.03125f : 1.0f;
#pragma unroll
    for (int mt = 0; mt < 2; ++mt) {
        const f32x16& sa = mt ? sacc1 : sacc0;
#pragma unroll
        for (int e = 0; e < 16; ++e) {
            const int b = mt*32 + (e&3) + 8*(e>>2) + 4*h;
            const float val = sa[e] * scale;
            if (ATOMIC) atomicAdd(sdst + (size_t)b*512 + colg, val);
            else        sdst[((size_t)blockIdx.x << 15) + (size_t)b*512 + colg] = val;
        }
    }
}

// ------------------------------------------------- reduction + squash kernels
__global__ __launch_bounds__(256)
void caps_reduce1(const float* __restrict__ sp, float* __restrict__ s2)
{
    const int e  = blockIdx.x * 256 + threadIdx.x;
    const int pg = blockIdx.y;
    const float* p0 = sp + (size_t)pg * 32 * SELEM + e;
    float a = 0.0f;
#pragma unroll 8
    for (int p = 0; p < 32; ++p) a += p0[(size_t)p * SELEM];
    s2[pg * SELEM + e] = a;
}

// mode 0: vsum = v; 1: vsum += v; 2: out = v.
__global__ __launch_bounds__(256)
void caps_reduce2(const float* __restrict__ src, int P,
                  float* __restrict__ vsum, float* __restrict__ out, int mode)
{
    const int e = blockIdx.x * 256 + threadIdx.x;
    float a = 0.0f;
    for (int p = 0; p < P; ++p) a += src[(size_t)p * SELEM + e];
    float sq = a * a;
#pragma unroll
    for (int off = 8; off >= 1; off >>= 1) sq += __shfl_xor(sq, off);
    const float n = sqrtf(sq);
    const float v = a * (sq / (1.0f + sq) / (n + 1e-8f));
    if (mode == 0)      vsum[e] = v;
    else if (mode == 1) vsum[e] += v;
    else                out[e] = v;
}

// ------------------------------------- tier-3 fallback: round-2 fp32 kernel
__device__ __forceinline__ void gload_lds16(const void* g, void* l) {
    __builtin_amdgcn_global_load_lds(
        (const __attribute__((address_space(1))) void*)g,
        (__attribute__((address_space(3))) void*)l, 16, 0, 0);
}

template<bool FIRST>
__global__ __launch_bounds__(1024, 4)
void caps_pass_f32(const float* __restrict__ x, const float* __restrict__ W,
                   const float* __restrict__ vsumg, float* __restrict__ sdst)
{
    __shared__ float wlds[2][8192];
    const int tid = threadIdx.x, lane = tid & 63;
    const int c = tid & 31, dh = (tid >> 5) & 1, w = tid >> 6;
    const int r0 = blockIdx.x * RB, b0 = w << 2;
    const int key = (c & 7) << 4;
    const int cb  = (c << 10) + (dh << 5);

    float sacc[4][8];
#pragma unroll
    for (int q = 0; q < 4; ++q)
#pragma unroll
        for (int k = 0; k < 8; ++k) sacc[q][k] = 0.0f;

    float vreg[4][8];
    if (!FIRST) {
#pragma unroll
        for (int q = 0; q < 4; ++q) {
            const float4* vp = (const float4*)(vsumg + ((((b0+q) << 5) + c) << 4) + (dh << 3));
            float4 a = vp[0], bq = vp[1];
            vreg[q][0]=a.x; vreg[q][1]=a.y; vreg[q][2]=a.z; vreg[q][3]=a.w;
            vreg[q][4]=bq.x; vreg[q][5]=bq.y; vreg[q][6]=bq.z; vreg[q][7]=bq.w;
        }
    }

    const int Dloc0 = (w << 11);
    const int lx0 = (lane << 4) ^ ((((w << 1))     & 7) << 4);
    const int lx1 = (lane << 4) ^ ((((w << 1) | 1) & 7) << 4);
    const int wu = __builtin_amdgcn_readfirstlane(w);
    const float* xw = x + (size_t)((wu << 2) * R_ + r0) * 16;

#define STAGE(buf, r)                                                              \
    do {                                                                           \
        const char* wr_ = (const char*)W + ((size_t)(r) << 15);                    \
        gload_lds16(wr_ + Dloc0        + lx0, (char*)wlds[buf] + Dloc0);           \
        gload_lds16(wr_ + Dloc0 + 1024 + lx1, (char*)wlds[buf] + Dloc0 + 1024);    \
    } while (0)

    STAGE(0, r0);
#pragma unroll 1
    for (int t = 0; t < RB; ++t) {
        const int cur = t & 1;
        if (t + 1 < RB) { STAGE(cur ^ 1, r0 + t + 1); asm volatile("s_waitcnt vmcnt(2)" ::: "memory"); }
        else            { asm volatile("s_waitcnt vmcnt(0)" ::: "memory"); }
        __builtin_amdgcn_s_barrier();
        __builtin_amdgcn_sched_barrier(0);

        const char* lb = (const char*)wlds[cur];
        float u[4][8];
#pragma unroll
        for (int q = 0; q < 4; ++q)
#pragma unroll
            for (int k = 0; k < 8; ++k) u[q][k] = 0.0f;

#pragma unroll
        for (int i = 0; i < 16; ++i) {
            const int A = (cb + (i << 6)) ^ key;
            float4 w0 = *(const float4*)(lb + A);
            float4 w1 = *(const float4*)(lb + (A ^ 16));
            float wv[8] = {w0.x, w0.y, w0.z, w0.w, w1.x, w1.y, w1.z, w1.w};
#pragma unroll
            for (int q = 0; q < 4; ++q) {
                const float xv = xw[(size_t)q * (R_ * 16) + t * 16 + i];
#pragma unroll
                for (int k = 0; k < 8; ++k) u[q][k] = fmaf(xv, wv[k], u[q][k]);
            }
        }

#pragma unroll
        for (int q = 0; q < 4; ++q) {
            float cij;
            if (FIRST) cij = 0.03125f;
            else {
                float th = 0.0f;
#pragma unroll
                for (int k = 0; k < 8; ++k) th = fmaf(u[q][k], vreg[q][k], th);
                th += __shfl_xor(th, 32);
                float m = th;
#pragma unroll
                for (int off = 16; off >= 1; off >>= 1) m = fmaxf(m, __shfl_xor(m, off));
                const float e = __expf(th - m);
                float ssum = e;
#pragma unroll
                for (int off = 16; off >= 1; off >>= 1) ssum += __shfl_xor(ssum, off);
                cij = e / ssum;
            }
#pragma unroll
            for (int k = 0; k < 8; ++k) sacc[q][k] = fmaf(cij, u[q][k], sacc[q][k]);
        }
        __builtin_amdgcn_s_barrier();
    }
#undef STAGE

#pragma unroll
    for (int q = 0; q < 4; ++q) {
        float* sp = sdst + ((((b0+q) << 5) + c) << 4) + (dh << 3);
#pragma unroll
        for (int k = 0; k < 8; ++k) atomicAdd(sp + k, sacc[q][k]);
    }
}

// ---------------------------------------------------------------- launcher
extern "C" void kernel_launch(void* const* d_in, const int* in_sizes, int n_in,
                              void* d_out, int out_size, void* d_ws, size_t ws_size,
                              hipStream_t stream)
{
    const float* x = (const float*)d_in[0];          // [64, 4608, 16]
    const float* W = (const float*)d_in[1];          // [4608, 32, 16, 16]
    float* out = (float*)d_out;                      // [64, 32, 16]

    const size_t WPB = (size_t)R_ * 16 * 64 * 8 * sizeof(_Float16);  // 75,497,472
    const size_t XBB = (size_t)B_ * R_ * 16 * sizeof(_Float16);      //  9,437,184
    const size_t SPB = (size_t)NBLK * SELEM * sizeof(float);         // 33,554,432
    const size_t S2B = (size_t)8 * SELEM * sizeof(float);
    const size_t VSB = (size_t)SELEM * sizeof(float);
    char* wsc = (char*)d_ws;

    if (ws_size >= WPB + XBB + SPB + S2B + VSB) {
        _Float16* wp  = (_Float16*)wsc;
        _Float16* xbp = (_Float16*)(wsc + WPB);
        float* s_part = (float*)(wsc + WPB + XBB);
        float* s2     = (float*)(wsc + WPB + XBB + SPB);
        float* vsum   = (float*)(wsc + WPB + XBB + SPB + S2B);

        caps_mfma<true,  false><<<NBLK, 1024, 0, stream>>>(x, W, xbp, wp, nullptr, s_part);
        caps_reduce1<<<dim3(128, 8), 256, 0, stream>>>(s_part, s2);
        caps_reduce2<<<128, 256, 0, stream>>>(s2, 8, vsum, nullptr, 0);

        caps_mfma<false, false><<<NBLK, 1024, 0, stream>>>(x, W, xbp, wp, vsum, s_part);
        caps_reduce1<<<dim3(128, 8), 256, 0, stream>>>(s_part, s2);
        caps_reduce2<<<128, 256, 0, stream>>>(s2, 8, vsum, nullptr, 1);

        caps_mfma<false, false><<<NBLK, 1024, 0, stream>>>(x, W, xbp, wp, vsum, s_part);
        caps_reduce1<<<dim3(128, 8), 256, 0, stream>>>(s_part, s2);
        caps_reduce2<<<128, 256, 0, stream>>>(s2, 8, nullptr, out, 2);
    } else if (ws_size >= WPB + XBB + 2*VSB) {
        _Float16* wp  = (_Float16*)wsc;
        _Float16* xbp = (_Float16*)(wsc + WPB);
        float* s    = (float*)(wsc + WPB + XBB);
        float* vsum = (float*)(wsc + WPB + XBB + VSB);

        hipMemsetAsync(s, 0, VSB, stream);
        caps_mfma<true,  true><<<NBLK, 1024, 0, stream>>>(x, W, xbp, wp, nullptr, s);
        caps_reduce2<<<128, 256, 0, stream>>>(s, 1, vsum, nullptr, 0);

        hipMemsetAsync(s, 0, VSB, stream);
        caps_mfma<false, true><<<NBLK, 1024, 0, stream>>>(x, W, xbp, wp, vsum, s);
        caps_reduce2<<<128, 256, 0, stream>>>(s, 1, vsum, nullptr, 1);

        hipMemsetAsync(s, 0, VSB, stream);
        caps_mfma<false, true><<<NBLK, 1024, 0, stream>>>(x, W, xbp, wp, vsum, s);
        caps_reduce2<<<128, 256, 0, stream>>>(s, 1, nullptr, out, 2);
    } else {
        // tiny-ws fallback: fp32 VALU path (round-2 kernel, atomic accumulate)
        float* s    = (float*)wsc;
        float* vsum = s + SELEM;

        hipMemsetAsync(s, 0, VSB, stream);
        caps_pass_f32<true><<<NBLK, 1024, 0, stream>>>(x, W, nullptr, s);
        caps_reduce2<<<128, 256, 0, stream>>>(s, 1, vsum, nullptr, 0);

        hipMemsetAsync(s, 0, VSB, stream);
        caps_pass_f32<false><<<NBLK, 1024, 0, stream>>>(x, W, vsum, s);
        caps_reduce2<<<128, 256, 0, stream>>>(s, 1, vsum, nullptr, 1);

        hipMemsetAsync(s, 0, VSB, stream);
        caps_pass_f32<false><<<NBLK, 1024, 0, stream>>>(x, W, vsum, s);
        caps_reduce2<<<128, 256, 0, stream>>>(s, 1, nullptr, out, 2);
    }
}

// Round 6
// 256.703 us; speedup vs baseline: 1.9205x; 1.1472x over previous
//
#include <hip/hip_runtime.h>
#include <math.h>

// Capsule dynamic routing, B=64, R=4608, C=32, Din=Dout=16, 3 iters.
// b-logits are linear in v -> keep only vsum[B,C,16]; u_hat recomputed per
// pass via mfma_f32_32x32x16_f16 (K=16==Din), never materialized.
//
// Round-6: fix round-5's x-LDS swizzle. Old key drew from bits 5-7 while
// XOR-targeting bits 4-6 (overlap -> not an involution -> wrong x rows).
// New key: source bits 7-9 (b-row bits), target bits 4-6 -> disjoint ->
// involution, and spreads the 8-way A-frag bank conflict to conflict-free.

#define B_    64
#define R_    4608
#define C_    32
#define RB    18
#define NBLK  (R_ / RB)      // 256
#define SELEM 32768          // B_*C_*16

typedef _Float16 half8  __attribute__((ext_vector_type(8)));
typedef _Float16 half2v __attribute__((ext_vector_type(2)));
typedef float    f32x16 __attribute__((ext_vector_type(16)));
typedef float    f32x4v __attribute__((ext_vector_type(4)));

__device__ __forceinline__ void gload_lds16(const void* g, void* l) {
    __builtin_amdgcn_global_load_lds(
        (const __attribute__((address_space(1))) void*)g,
        (__attribute__((address_space(3))) void*)l, 16, 0, 0);
}

// ------------------------------------------------------------------ prep
// x [64][4608][16] f32  ->  xa [4608][64][16] f16
__global__ __launch_bounds__(256)
void caps_prep(const float* __restrict__ x, _Float16* __restrict__ xa)
{
    const int idx = blockIdx.x * 256 + threadIdx.x;   // idx = r*64 + b
    const int r = idx >> 6, b = idx & 63;
    const float4* xs = (const float4*)(x + ((size_t)b * R_ + r) * 16);
    const float4 A = xs[0], Bv = xs[1], Cv = xs[2], Dv = xs[3];
    half8 lo, hi;
    lo[0]=(_Float16)A.x;  lo[1]=(_Float16)A.y;  lo[2]=(_Float16)A.z;  lo[3]=(_Float16)A.w;
    lo[4]=(_Float16)Bv.x; lo[5]=(_Float16)Bv.y; lo[6]=(_Float16)Bv.z; lo[7]=(_Float16)Bv.w;
    hi[0]=(_Float16)Cv.x; hi[1]=(_Float16)Cv.y; hi[2]=(_Float16)Cv.z; hi[3]=(_Float16)Cv.w;
    hi[4]=(_Float16)Dv.x; hi[5]=(_Float16)Dv.y; hi[6]=(_Float16)Dv.z; hi[7]=(_Float16)Dv.w;
    half8* dst = (half8*)(xa + ((size_t)idx << 4));
    dst[0] = lo; dst[1] = hi;
}

// ------------------------------------------------------------- MFMA pass
// C/D layout (m74/m101): col = lane&31, row = (reg&3)+8*(reg>>2)+4*(lane>>5).
// A: lane holds A[row=lane&31][k=8*(lane>>5)+e]; B: B[k][col=lane&31].
template<bool FIRST, bool ATOMIC>
__global__ __launch_bounds__(512, 4)
void caps_mfma(const _Float16* __restrict__ xa, const float* __restrict__ W,
               _Float16* __restrict__ wp, const float* __restrict__ vsumg,
               float* __restrict__ sdst)
{
    __shared__ _Float16 xalds[RB * 512];      // [18][32 b][16 i] = 18 KB
    __shared__ float t_lds[32][36];           // padded: 16B-aligned rows
    __shared__ float c_lds[32][36];

    const int tid  = threadIdx.x;
    const int lane = tid & 63;
    const int wv   = tid >> 6;                // 0..7
    const int h    = lane >> 5;
    const int l31  = lane & 31;
    const int ch   = l31 >> 4;                // which capsule within a col-tile
    const int bh   = blockIdx.y;              // b-half: 0 -> b 0..31, 1 -> 32..63
    const int r0   = blockIdx.x * RB;

    // ---- stage x tile (coalesced; swizzle f(L)=L^(((L>>7)&7)<<4), an
    // involution: source bits 7-9 disjoint from target bits 4-6) ----
    {
        const int slx = (lane << 4) ^ (((lane >> 3) & 7) << 4);
        for (int t = wv; t < RB; t += 8) {
            const char* src = (const char*)xa + (size_t)(r0 + t) * 2048 + bh * 1024 + slx;
            gload_lds16(src, (char*)xalds + t * 1024);
        }
    }

    f32x16 sacc0, sacc1, zf;
#pragma unroll
    for (int k = 0; k < 16; ++k) { sacc0[k] = 0.f; sacc1[k] = 0.f; zf[k] = 0.f; }

    // vsum fragments (f16-packed): vh[j][e2] = {v(e=2e2), v(e=2e2+1)}
    half2v vh[2][8];
    if (!FIRST) {
#pragma unroll
        for (int j = 0; j < 2; ++j) {
            const int colg = (2*wv + j) * 32 + l31;
#pragma unroll
            for (int e2 = 0; e2 < 8; ++e2) {
                const int eA = 2*e2, eB = 2*e2 + 1;
                const int bA = bh*32 + (eA&3) + 8*(eA>>2) + 4*h;
                const int bB = bh*32 + (eB&3) + 8*(eB>>2) + 4*h;
                half2v tv;
                tv[0] = (_Float16)vsumg[(size_t)bA*512 + colg];
                tv[1] = (_Float16)vsumg[(size_t)bB*512 + colg];
                vh[j][e2] = tv;
            }
        }
    }

    asm volatile("s_waitcnt vmcnt(0)" ::: "memory");
    __syncthreads();

    // A-frag read offset: P = l31*32 + h*16, read LDS[f(P)]
    const int avoff = ((l31 << 5) + (h << 4)) ^ (((l31 >> 2) & 7) << 4);

    half8 bc0, bc1;
    if (!FIRST) {
        bc0 = *(const half8*)(wp + (((size_t)r0*16 + 2*wv    )*64 + lane)*8);
        bc1 = *(const half8*)(wp + (((size_t)r0*16 + 2*wv + 1)*64 + lane)*8);
    }

#pragma unroll 1
    for (int t = 0; t < RB; ++t) {
        const half8 av = *(const half8*)((const char*)xalds + t*1024 + avoff);

        if (FIRST) {
            const int r = r0 + t;
            half8 bf0, bf1;
            const float* ws0 = W + (((size_t)r*32 + (4*wv     + ch))*16 + 8*h)*16 + (l31 & 15);
            const float* ws1 = W + (((size_t)r*32 + (4*wv + 2 + ch))*16 + 8*h)*16 + (l31 & 15);
#pragma unroll
            for (int e = 0; e < 8; ++e) {
                bf0[e] = (_Float16)ws0[e*16];
                bf1[e] = (_Float16)ws1[e*16];
            }
            if (bh == 0) {
                *(half8*)(wp + (((size_t)r*16 + 2*wv    )*64 + lane)*8) = bf0;
                *(half8*)(wp + (((size_t)r*16 + 2*wv + 1)*64 + lane)*8) = bf1;
            }
            sacc0 = __builtin_amdgcn_mfma_f32_32x32x16_f16(av, bf0, sacc0, 0, 0, 0);
            sacc1 = __builtin_amdgcn_mfma_f32_32x32x16_f16(av, bf1, sacc1, 0, 0, 0);
            continue;
        }

        const f32x16 u0 = __builtin_amdgcn_mfma_f32_32x32x16_f16(av, bc0, zf, 0, 0, 0);
        const f32x16 u1 = __builtin_amdgcn_mfma_f32_32x32x16_f16(av, bc1, zf, 0, 0, 0);

        // prefetch next r's B-frags (clamped tail re-load is harmless)
        const int tn = (t < RB-1) ? (t+1) : t;
        bc0 = *(const half8*)(wp + (((size_t)(r0+tn)*16 + 2*wv    )*64 + lane)*8);
        bc1 = *(const half8*)(wp + (((size_t)(r0+tn)*16 + 2*wv + 1)*64 + lane)*8);

        // ---- logits: o-reduce via 15-shfl reduce-scatter (static idx only)
        float tvj[2];
#pragma unroll
        for (int j = 0; j < 2; ++j) {
            const f32x16& u = j ? u1 : u0;
            float p[16];
#pragma unroll
            for (int e2 = 0; e2 < 8; ++e2) {
                p[2*e2]   = u[2*e2]   * (float)vh[j][e2][0];
                p[2*e2+1] = u[2*e2+1] * (float)vh[j][e2][1];
            }
            float q8[8];
#pragma unroll
            for (int q = 0; q < 8; ++q) {
                const float aa = p[q], bb = p[8+q];
                const float keep = (lane & 1) ? bb : aa;
                const float send = (lane & 1) ? aa : bb;
                q8[q] = keep + __shfl_xor(send, 1);
            }
            float q4[4];
#pragma unroll
            for (int q = 0; q < 4; ++q) {
                const float aa = q8[q], bb = q8[4+q];
                const float keep = (lane & 2) ? bb : aa;
                const float send = (lane & 2) ? aa : bb;
                q4[q] = keep + __shfl_xor(send, 2);
            }
            float q2[2];
#pragma unroll
            for (int q = 0; q < 2; ++q) {
                const float aa = q4[q], bb = q4[2+q];
                const float keep = (lane & 4) ? bb : aa;
                const float send = (lane & 4) ? aa : bb;
                q2[q] = keep + __shfl_xor(send, 4);
            }
            {
                const float aa = q2[0], bb = q2[1];
                const float keep = (lane & 8) ? bb : aa;
                const float send = (lane & 8) ? aa : bb;
                tvj[j] = keep + __shfl_xor(send, 8);
            }
        }
        {   // lane holds t of local row es = bitrev4(lane&15)
            const int es  = ((lane&1)<<3) | ((lane&2)<<1) | ((lane&4)>>1) | ((lane&8)>>3);
            const int bb0 = (es&3) + 8*(es>>2) + 4*h;
            t_lds[4*wv     + ch][bb0] = tvj[0];
            t_lds[4*wv + 2 + ch][bb0] = tvj[1];
        }
        __syncthreads();

        // ---- softmax over c: thread -> (c-pair 2a_,2a_+1; local b2) ----
        {
            const int a_ = lane & 15;
            const int b2 = 4*wv + (lane >> 4);
            const float tA = t_lds[2*a_][b2];
            const float tB = t_lds[2*a_+1][b2];
            float m = fmaxf(tA, tB);
            m = fmaxf(m, __shfl_xor(m, 1));
            m = fmaxf(m, __shfl_xor(m, 2));
            m = fmaxf(m, __shfl_xor(m, 4));
            m = fmaxf(m, __shfl_xor(m, 8));
            const float eA = __expf(tA - m);
            const float eB = __expf(tB - m);
            float zs = eA + eB;
            zs += __shfl_xor(zs, 1);
            zs += __shfl_xor(zs, 2);
            zs += __shfl_xor(zs, 4);
            zs += __shfl_xor(zs, 8);
            const float inv = 1.0f / zs;
            c_lds[2*a_][b2]   = eA * inv;
            c_lds[2*a_+1][b2] = eB * inv;
        }
        __syncthreads();

        // ---- accumulate: sacc += c_ij * u (broadcast b128 reads, free) ----
#pragma unroll
        for (int j = 0; j < 2; ++j) {
            const f32x16& u = j ? u1 : u0;
            f32x16& sa = j ? sacc1 : sacc0;
            const float* cp = &c_lds[4*wv + 2*j + ch][4*h];
#pragma unroll
            for (int k = 0; k < 4; ++k) {
                const f32x4v cc = *(const f32x4v*)(cp + 8*k);
#pragma unroll
                for (int q = 0; q < 4; ++q)
                    sa[4*k+q] += cc[q] * u[4*k+q];
            }
        }
    }

    // ---- epilogue ----
    const float scale = FIRST ? 0.03125f : 1.0f;
#pragma unroll
    for (int j = 0; j < 2; ++j) {
        const f32x16& sa = j ? sacc1 : sacc0;
        const int colg = (2*wv + j) * 32 + l31;
#pragma unroll
        for (int e = 0; e < 16; ++e) {
            const int b = bh*32 + (e&3) + 8*(e>>2) + 4*h;
            const float val = sa[e] * scale;
            if (ATOMIC) atomicAdd(sdst + (size_t)b*512 + colg, val);
            else        sdst[((size_t)blockIdx.x << 15) + (size_t)b*512 + colg] = val;
        }
    }
}

// ------------------------------------------------- reduction + squash
__global__ __launch_bounds__(256)
void caps_reduce1(const float* __restrict__ sp, float* __restrict__ s2)
{
    const int e  = blockIdx.x * 256 + threadIdx.x;
    const int pg = blockIdx.y;
    const float* p0 = sp + (size_t)pg * 32 * SELEM + e;
    float a = 0.0f;
#pragma unroll 8
    for (int p = 0; p < 32; ++p) a += p0[(size_t)p * SELEM];
    s2[pg * SELEM + e] = a;
}

// mode 0: vsum = v; 1: vsum += v; 2: out = v.
__global__ __launch_bounds__(256)
void caps_reduce2(const float* __restrict__ src, int P,
                  float* __restrict__ vsum, float* __restrict__ out, int mode)
{
    const int e = blockIdx.x * 256 + threadIdx.x;
    float a = 0.0f;
    for (int p = 0; p < P; ++p) a += src[(size_t)p * SELEM + e];
    float sq = a * a;
#pragma unroll
    for (int off = 8; off >= 1; off >>= 1) sq += __shfl_xor(sq, off);
    const float n = sqrtf(sq);
    const float v = a * (sq / (1.0f + sq) / (n + 1e-8f));
    if (mode == 0)      vsum[e] = v;
    else if (mode == 1) vsum[e] += v;
    else                out[e] = v;
}

// ------------------------------------- tier-3 fallback: fp32 VALU path
template<bool FIRST>
__global__ __launch_bounds__(1024, 4)
void caps_pass_f32(const float* __restrict__ x, const float* __restrict__ W,
                   const float* __restrict__ vsumg, float* __restrict__ sdst)
{
    __shared__ float wlds[2][8192];
    const int tid = threadIdx.x, lane = tid & 63;
    const int c = tid & 31, dh = (tid >> 5) & 1, w = tid >> 6;
    const int r0 = blockIdx.x * RB, b0 = w << 2;
    const int key = (c & 7) << 4;
    const int cb  = (c << 10) + (dh << 5);

    float sacc[4][8];
#pragma unroll
    for (int q = 0; q < 4; ++q)
#pragma unroll
        for (int k = 0; k < 8; ++k) sacc[q][k] = 0.0f;

    float vreg[4][8];
    if (!FIRST) {
#pragma unroll
        for (int q = 0; q < 4; ++q) {
            const float4* vp = (const float4*)(vsumg + ((((b0+q) << 5) + c) << 4) + (dh << 3));
            float4 a = vp[0], bq = vp[1];
            vreg[q][0]=a.x; vreg[q][1]=a.y; vreg[q][2]=a.z; vreg[q][3]=a.w;
            vreg[q][4]=bq.x; vreg[q][5]=bq.y; vreg[q][6]=bq.z; vreg[q][7]=bq.w;
        }
    }

    const int Dloc0 = (w << 11);
    const int lx0 = (lane << 4) ^ ((((w << 1))     & 7) << 4);
    const int lx1 = (lane << 4) ^ ((((w << 1) | 1) & 7) << 4);
    const int wu = __builtin_amdgcn_readfirstlane(w);
    const float* xw = x + (size_t)((wu << 2) * R_ + r0) * 16;

#define STAGE(buf, r)                                                              \
    do {                                                                           \
        const char* wr_ = (const char*)W + ((size_t)(r) << 15);                    \
        gload_lds16(wr_ + Dloc0        + lx0, (char*)wlds[buf] + Dloc0);           \
        gload_lds16(wr_ + Dloc0 + 1024 + lx1, (char*)wlds[buf] + Dloc0 + 1024);    \
    } while (0)

    STAGE(0, r0);
#pragma unroll 1
    for (int t = 0; t < RB; ++t) {
        const int cur = t & 1;
        if (t + 1 < RB) { STAGE(cur ^ 1, r0 + t + 1); asm volatile("s_waitcnt vmcnt(2)" ::: "memory"); }
        else            { asm volatile("s_waitcnt vmcnt(0)" ::: "memory"); }
        __builtin_amdgcn_s_barrier();
        __builtin_amdgcn_sched_barrier(0);

        const char* lb = (const char*)wlds[cur];
        float u[4][8];
#pragma unroll
        for (int q = 0; q < 4; ++q)
#pragma unroll
            for (int k = 0; k < 8; ++k) u[q][k] = 0.0f;

#pragma unroll
        for (int i = 0; i < 16; ++i) {
            const int A = (cb + (i << 6)) ^ key;
            float4 w0 = *(const float4*)(lb + A);
            float4 w1 = *(const float4*)(lb + (A ^ 16));
            float wv[8] = {w0.x, w0.y, w0.z, w0.w, w1.x, w1.y, w1.z, w1.w};
#pragma unroll
            for (int q = 0; q < 4; ++q) {
                const float xv = xw[(size_t)q * (R_ * 16) + t * 16 + i];
#pragma unroll
                for (int k = 0; k < 8; ++k) u[q][k] = fmaf(xv, wv[k], u[q][k]);
            }
        }

#pragma unroll
        for (int q = 0; q < 4; ++q) {
            float cij;
            if (FIRST) cij = 0.03125f;
            else {
                float th = 0.0f;
#pragma unroll
                for (int k = 0; k < 8; ++k) th = fmaf(u[q][k], vreg[q][k], th);
                th += __shfl_xor(th, 32);
                float m = th;
#pragma unroll
                for (int off = 16; off >= 1; off >>= 1) m = fmaxf(m, __shfl_xor(m, off));
                const float e = __expf(th - m);
                float ssum = e;
#pragma unroll
                for (int off = 16; off >= 1; off >>= 1) ssum += __shfl_xor(ssum, off);
                cij = e / ssum;
            }
#pragma unroll
            for (int k = 0; k < 8; ++k) sacc[q][k] = fmaf(cij, u[q][k], sacc[q][k]);
        }
        __builtin_amdgcn_s_barrier();
    }
#undef STAGE

#pragma unroll
    for (int q = 0; q < 4; ++q) {
        float* sp = sdst + ((((b0+q) << 5) + c) << 4) + (dh << 3);
#pragma unroll
        for (int k = 0; k < 8; ++k) atomicAdd(sp + k, sacc[q][k]);
    }
}

// ---------------------------------------------------------------- launcher
extern "C" void kernel_launch(void* const* d_in, const int* in_sizes, int n_in,
                              void* d_out, int out_size, void* d_ws, size_t ws_size,
                              hipStream_t stream)
{
    const float* x = (const float*)d_in[0];          // [64, 4608, 16]
    const float* W = (const float*)d_in[1];          // [4608, 32, 16, 16]
    float* out = (float*)d_out;                      // [64, 32, 16]

    const size_t WPB = (size_t)R_ * 16 * 64 * 8 * sizeof(_Float16);  // 75,497,472
    const size_t XAB = (size_t)R_ * 64 * 16 * sizeof(_Float16);      //  9,437,184
    const size_t SPB = (size_t)NBLK * SELEM * sizeof(float);         // 33,554,432
    const size_t S2B = (size_t)8 * SELEM * sizeof(float);
    const size_t VSB = (size_t)SELEM * sizeof(float);
    char* wsc = (char*)d_ws;
    const dim3 pgrid(NBLK, 2);

    if (ws_size >= WPB + XAB + SPB + S2B + VSB) {
        _Float16* wp  = (_Float16*)wsc;
        _Float16* xa  = (_Float16*)(wsc + WPB);
        float* s_part = (float*)(wsc + WPB + XAB);
        float* s2     = (float*)(wsc + WPB + XAB + SPB);
        float* vsum   = (float*)(wsc + WPB + XAB + SPB + S2B);

        caps_prep<<<1152, 256, 0, stream>>>(x, xa);

        caps_mfma<true,  false><<<pgrid, 512, 0, stream>>>(xa, W, wp, nullptr, s_part);
        caps_reduce1<<<dim3(128, 8), 256, 0, stream>>>(s_part, s2);
        caps_reduce2<<<128, 256, 0, stream>>>(s2, 8, vsum, nullptr, 0);

        caps_mfma<false, false><<<pgrid, 512, 0, stream>>>(xa, W, wp, vsum, s_part);
        caps_reduce1<<<dim3(128, 8), 256, 0, stream>>>(s_part, s2);
        caps_reduce2<<<128, 256, 0, stream>>>(s2, 8, vsum, nullptr, 1);

        caps_mfma<false, false><<<pgrid, 512, 0, stream>>>(xa, W, wp, vsum, s_part);
        caps_reduce1<<<dim3(128, 8), 256, 0, stream>>>(s_part, s2);
        caps_reduce2<<<128, 256, 0, stream>>>(s2, 8, nullptr, out, 2);
    } else if (ws_size >= WPB + XAB + 2*VSB) {
        _Float16* wp = (_Float16*)wsc;
        _Float16* xa = (_Float16*)(wsc + WPB);
        float* s     = (float*)(wsc + WPB + XAB);
        float* vsum  = (float*)(wsc + WPB + XAB + VSB);

        caps_prep<<<1152, 256, 0, stream>>>(x, xa);

        hipMemsetAsync(s, 0, VSB, stream);
        caps_mfma<true,  true><<<pgrid, 512, 0, stream>>>(xa, W, wp, nullptr, s);
        caps_reduce2<<<128, 256, 0, stream>>>(s, 1, vsum, nullptr, 0);

        hipMemsetAsync(s, 0, VSB, stream);
        caps_mfma<false, true><<<pgrid, 512, 0, stream>>>(xa, W, wp, vsum, s);
        caps_reduce2<<<128, 256, 0, stream>>>(s, 1, vsum, nullptr, 1);

        hipMemsetAsync(s, 0, VSB, stream);
        caps_mfma<false, true><<<pgrid, 512, 0, stream>>>(xa, W, wp, vsum, s);
        caps_reduce2<<<128, 256, 0, stream>>>(s, 1, nullptr, out, 2);
    } else {
        // tiny-ws fallback: fp32 VALU path (atomic accumulate)
        float* s    = (float*)wsc;
        float* vsum = s + SELEM;

        hipMemsetAsync(s, 0, VSB, stream);
        caps_pass_f32<true><<<NBLK, 1024, 0, stream>>>(x, W, nullptr, s);
        caps_reduce2<<<128, 256, 0, stream>>>(s, 1, vsum, nullptr, 0);

        hipMemsetAsync(s, 0, VSB, stream);
        caps_pass_f32<false><<<NBLK, 1024, 0, stream>>>(x, W, vsum, s);
        caps_reduce2<<<128, 256, 0, stream>>>(s, 1, vsum, nullptr, 1);

        hipMemsetAsync(s, 0, VSB, stream);
        caps_pass_f32<false><<<NBLK, 1024, 0, stream>>>(x, W, vsum, s);
        caps_reduce2<<<128, 256, 0, stream>>>(s, 1, nullptr, out, 2);
    }
}

// Round 7
// 156.717 us; speedup vs baseline: 3.1458x; 1.6380x over previous
//
#include <hip/hip_runtime.h>
#include <math.h>

// Capsule dynamic routing, B=64, R=4608, C=32, Din=Dout=16, 3 iters.
// b-logits are linear in v -> keep only vsum; u_hat recomputed per pass via
// mfma_f32_32x32x16_f16 (K=16==Din), never materialized.
//
// Round-7: swap MFMA operands: u^T = mfma(A=Wfrag, B=xfrag) -> D[(c,o)][b].
// Per-lane A/B fragment ownership is symmetric, so wp + xalds are unchanged;
// the o-reduction for logits moves into registers (4 shfl/r/wave instead of
// 30 ds_swizzle). s/vsum/out use transposed [512][64] layout; reduce2T squash
// is shuffle-free. W f32->f16 fragment conversion moves to a dedicated
// bandwidth-bound wprep kernel (coalesced in, LDS transpose, b128 out), so
// pass 1 becomes a pure GEMM with MFMA-C accumulation.

#define B_    64
#define R_    4608
#define C_    32
#define RB    18
#define NBLK  (R_ / RB)      // 256
#define SELEM 32768          // 512 * 64

typedef _Float16 half8  __attribute__((ext_vector_type(8)));
typedef _Float16 half2v __attribute__((ext_vector_type(2)));
typedef float    f32x16 __attribute__((ext_vector_type(16)));

__device__ __forceinline__ void gload_lds16(const void* g, void* l) {
    __builtin_amdgcn_global_load_lds(
        (const __attribute__((address_space(1))) void*)g,
        (__attribute__((address_space(3))) void*)l, 16, 0, 0);
}

// ------------------------------------------------------------------ prep
// x [64][4608][16] f32  ->  xa [4608][64][16] f16
__global__ __launch_bounds__(256)
void caps_prep(const float* __restrict__ x, _Float16* __restrict__ xa)
{
    const int idx = blockIdx.x * 256 + threadIdx.x;   // idx = r*64 + b
    const int r = idx >> 6, b = idx & 63;
    const float4* xs = (const float4*)(x + ((size_t)b * R_ + r) * 16);
    const float4 A = xs[0], Bv = xs[1], Cv = xs[2], Dv = xs[3];
    half8 lo, hi;
    lo[0]=(_Float16)A.x;  lo[1]=(_Float16)A.y;  lo[2]=(_Float16)A.z;  lo[3]=(_Float16)A.w;
    lo[4]=(_Float16)Bv.x; lo[5]=(_Float16)Bv.y; lo[6]=(_Float16)Bv.z; lo[7]=(_Float16)Bv.w;
    hi[0]=(_Float16)Cv.x; hi[1]=(_Float16)Cv.y; hi[2]=(_Float16)Cv.z; hi[3]=(_Float16)Cv.w;
    hi[4]=(_Float16)Dv.x; hi[5]=(_Float16)Dv.y; hi[6]=(_Float16)Dv.z; hi[7]=(_Float16)Dv.w;
    half8* dst = (half8*)(xa + ((size_t)idx << 4));
    dst[0] = lo; dst[1] = hi;
}

// ------------------------------------------------------------------ wprep
// W [4608][32][16][16] f32 -> wp fragment order f16:
// wp[((r*16+nt)*64+lane)*8+e] = W[r][2nt+(l31>>4)][8h+e][l31&15]
// Coalesced global_load_lds in, strided LDS reads (<=4-way, hidden under BW),
// b128 stores out. 2 r per block, 512 threads.
__global__ __launch_bounds__(512)
void caps_wprep(const float* __restrict__ W, _Float16* __restrict__ wp)
{
    __shared__ float wl[2][8192];             // 2 x 32 KB
    const int tid = threadIdx.x;
    const int rb  = blockIdx.x * 2;

#pragma unroll
    for (int rr = 0; rr < 2; ++rr)
#pragma unroll
        for (int k = 0; k < 4; ++k)
            gload_lds16((const char*)W + (size_t)(rb + rr) * 32768 + k * 8192 + tid * 16,
                        (char*)wl[rr] + k * 8192 + tid * 16);
    asm volatile("s_waitcnt vmcnt(0)" ::: "memory");
    __syncthreads();

    const int lane = tid & 63;
    const int h    = lane >> 5;
    const int l31  = lane & 31;
    const int o    = l31 & 15;

#pragma unroll
    for (int rr = 0; rr < 2; ++rr) {
#pragma unroll
        for (int ci = 0; ci < 2; ++ci) {
            const int nt = ci * 8 + (tid >> 6);
            const int c  = 2 * nt + (l31 >> 4);
            half8 f;
#pragma unroll
            for (int e = 0; e < 8; ++e)
                f[e] = (_Float16)wl[rr][c * 256 + (8 * h + e) * 16 + o];
            *(half8*)(wp + (((size_t)(rb + rr) * 16 + nt) * 64 + lane) * 8) = f;
        }
    }
}

// ------------------------------------------------------------- MFMA pass
// D = mfma(A=Wfrag, B=xfrag): D[row=(cc,o)][col=b_loc].
// lane: col b_loc = lane&31; rows (regs): R(e,h) = (e&3)+8*(e>>2)+4*h.
// global row g = (2wv+j)*32 + R -> c = g>>4, o = g&15.
template<bool FIRST>
__global__ __launch_bounds__(512, 4)
void caps_mfma(const _Float16* __restrict__ xa, const _Float16* __restrict__ wp,
               const float* __restrict__ vsumT, float* __restrict__ sdst)
{
    __shared__ _Float16 xalds[RB * 512];      // 18 KB
    __shared__ float t_lds[32][33];
    __shared__ float c_lds[32][33];

    const int tid  = threadIdx.x;
    const int lane = tid & 63;
    const int wv   = tid >> 6;                // 0..7
    const int h    = lane >> 5;
    const int l31  = lane & 31;
    const int bh   = blockIdx.y;              // b-half
    const int r0   = blockIdx.x * RB;
    const int bg   = bh * 32 + l31;           // global b owned by this lane

    // stage x tile (coalesced; involution swizzle validated in round 6)
    {
        const int slx = (lane << 4) ^ (((lane >> 3) & 7) << 4);
        for (int t = wv; t < RB; t += 8) {
            const char* src = (const char*)xa + (size_t)(r0 + t) * 2048 + bh * 1024 + slx;
            gload_lds16(src, (char*)xalds + t * 1024);
        }
    }

    f32x16 sacc0, sacc1, zf;
#pragma unroll
    for (int k = 0; k < 16; ++k) { sacc0[k] = 0.f; sacc1[k] = 0.f; zf[k] = 0.f; }

    // v[b][c][o] per lane, f16-packed (16 VGPRs): vh[j][e>>1][e&1] = v at reg e
    half2v vh[2][8];
    if (!FIRST) {
#pragma unroll
        for (int j = 0; j < 2; ++j)
#pragma unroll
            for (int e = 0; e < 16; ++e) {
                const int g = (2 * wv + j) * 32 + (e & 3) + 8 * (e >> 2) + 4 * h;
                vh[j][e >> 1][e & 1] = (_Float16)vsumT[(size_t)g * 64 + bg];
            }
    }

    asm volatile("s_waitcnt vmcnt(0)" ::: "memory");
    __syncthreads();

    const int avoff = ((l31 << 5) + (h << 4)) ^ (((l31 >> 2) & 7) << 4);

    const size_t wstride = 16 * 64 * 8;       // f16 per r
    const _Float16* wpb = wp + (((size_t)r0 * 16 + 2 * wv) * 64 + lane) * 8;
    half8 bc0 = *(const half8*)wpb;
    half8 bc1 = *(const half8*)(wpb + 512);

#pragma unroll 1
    for (int t = 0; t < RB; ++t) {
        const half8 av = *(const half8*)((const char*)xalds + t * 1024 + avoff);

        f32x16 u0, u1;
        if (FIRST) {
            sacc0 = __builtin_amdgcn_mfma_f32_32x32x16_f16(bc0, av, sacc0, 0, 0, 0);
            sacc1 = __builtin_amdgcn_mfma_f32_32x32x16_f16(bc1, av, sacc1, 0, 0, 0);
        } else {
            u0 = __builtin_amdgcn_mfma_f32_32x32x16_f16(bc0, av, zf, 0, 0, 0);
            u1 = __builtin_amdgcn_mfma_f32_32x32x16_f16(bc1, av, zf, 0, 0, 0);
        }

        // prefetch next r's W-frags (clamped tail re-load harmless)
        const int tn = (t < RB - 1) ? (t + 1) : t;
        const _Float16* wpn = wp + ((size_t)(r0 + tn)) * wstride + ((size_t)(2 * wv) * 64 + lane) * 8;
        bc0 = *(const half8*)wpn;
        bc1 = *(const half8*)(wpn + 512);

        if (FIRST) continue;

        // ---- logits: in-register o-reduce + one half-swap fold per capsule
        float tc[2][2];
#pragma unroll
        for (int j = 0; j < 2; ++j) {
            const f32x16& u = j ? u1 : u0;
            float s0 = 0.f, s1 = 0.f;
#pragma unroll
            for (int e2 = 0; e2 < 4; ++e2) {
                s0 += u[2 * e2]     * (float)vh[j][e2][0];
                s0 += u[2 * e2 + 1] * (float)vh[j][e2][1];
                s1 += u[8 + 2 * e2]     * (float)vh[j][4 + e2][0];
                s1 += u[8 + 2 * e2 + 1] * (float)vh[j][4 + e2][1];
            }
            s0 += __shfl_xor(s0, 32);
            s1 += __shfl_xor(s1, 32);
            tc[j][0] = s0; tc[j][1] = s1;
        }
        if (h == 0) {
            t_lds[4 * wv    ][l31] = tc[0][0];
            t_lds[4 * wv + 1][l31] = tc[0][1];
            t_lds[4 * wv + 2][l31] = tc[1][0];
            t_lds[4 * wv + 3][l31] = tc[1][1];
        }
        __syncthreads();

        // ---- softmax over c: thread -> (c-pair a_, local b2) ----
        {
            const int a_ = lane & 15;
            const int b2 = tid >> 4;          // 0..31
            const float tA = t_lds[2 * a_][b2];
            const float tB = t_lds[2 * a_ + 1][b2];
            float m = fmaxf(tA, tB);
            m = fmaxf(m, __shfl_xor(m, 1));
            m = fmaxf(m, __shfl_xor(m, 2));
            m = fmaxf(m, __shfl_xor(m, 4));
            m = fmaxf(m, __shfl_xor(m, 8));
            const float eA = __expf(tA - m);
            const float eB = __expf(tB - m);
            float zs = eA + eB;
            zs += __shfl_xor(zs, 1);
            zs += __shfl_xor(zs, 2);
            zs += __shfl_xor(zs, 4);
            zs += __shfl_xor(zs, 8);
            const float inv = 1.0f / zs;
            c_lds[2 * a_][b2]     = eA * inv;
            c_lds[2 * a_ + 1][b2] = eB * inv;
        }
        __syncthreads();

        // ---- accumulate: sacc += c_ij * u (2 broadcast b32 reads per tile)
#pragma unroll
        for (int j = 0; j < 2; ++j) {
            const f32x16& u = j ? u1 : u0;
            f32x16& sa = j ? sacc1 : sacc0;
            const float c0v = c_lds[4 * wv + 2 * j    ][l31];
            const float c1v = c_lds[4 * wv + 2 * j + 1][l31];
#pragma unroll
            for (int e = 0; e < 8; ++e)  sa[e]     += c0v * u[e];
#pragma unroll
            for (int e = 8; e < 16; ++e) sa[e]     += c1v * u[e];
        }
    }

    // ---- epilogue: transposed partial store sT[g][b] (coalesced over b) ----
    const float scale = FIRST ? 0.03125f : 1.0f;
    float* sp = sdst + ((size_t)blockIdx.x << 15);
#pragma unroll
    for (int j = 0; j < 2; ++j) {
        const f32x16& sa = j ? sacc1 : sacc0;
#pragma unroll
        for (int e = 0; e < 16; ++e) {
            const int g = (2 * wv + j) * 32 + (e & 3) + 8 * (e >> 2) + 4 * h;
            sp[(size_t)g * 64 + bg] = sa[e] * scale;
        }
    }
}

// ------------------------------------------------- reductions + squash
// stage 1: 256 partials -> 8 (elementwise, layout-agnostic)
__global__ __launch_bounds__(256)
void caps_reduce1(const float* __restrict__ sp, float* __restrict__ s2)
{
    const int e  = blockIdx.x * 256 + threadIdx.x;
    const int pg = blockIdx.y;
    const float* p0 = sp + (size_t)pg * 32 * SELEM + e;
    float a = 0.0f;
#pragma unroll 8
    for (int p = 0; p < 32; ++p) a += p0[(size_t)p * SELEM];
    s2[pg * SELEM + e] = a;
}

// stage 2 on transposed layout: thread owns (c,b), o in registers -> no shfl.
// mode 0: vsumT = v; 1: vsumT += v; 2: out[b][c][o] = v.
__global__ __launch_bounds__(64)
void caps_reduce2T(const float* __restrict__ src, float* __restrict__ vsumT,
                   float* __restrict__ out, int mode)
{
    const int c = blockIdx.x;                 // 0..31
    const int b = threadIdx.x;                // 0..63
    float a[16];
#pragma unroll
    for (int o = 0; o < 16; ++o) a[o] = 0.0f;
    for (int p = 0; p < 8; ++p)
#pragma unroll
        for (int o = 0; o < 16; ++o)
            a[o] += src[(size_t)p * SELEM + c * 1024 + o * 64 + b];
    float sq = 0.0f;
#pragma unroll
    for (int o = 0; o < 16; ++o) sq += a[o] * a[o];
    const float n  = sqrtf(sq);
    const float sc = sq / (1.0f + sq) / (n + 1e-8f);
    if (mode == 2) {
#pragma unroll
        for (int o = 0; o < 16; ++o)
            out[(size_t)b * 512 + c * 16 + o] = a[o] * sc;
    } else if (mode == 0) {
#pragma unroll
        for (int o = 0; o < 16; ++o)
            vsumT[c * 1024 + o * 64 + b] = a[o] * sc;
    } else {
#pragma unroll
        for (int o = 0; o < 16; ++o)
            vsumT[c * 1024 + o * 64 + b] += a[o] * sc;
    }
}

// old-layout reduce2 (tier-3 fallback only)
__global__ __launch_bounds__(256)
void caps_reduce2(const float* __restrict__ src, int P,
                  float* __restrict__ vsum, float* __restrict__ out, int mode)
{
    const int e = blockIdx.x * 256 + threadIdx.x;
    float a = 0.0f;
    for (int p = 0; p < P; ++p) a += src[(size_t)p * SELEM + e];
    float sq = a * a;
#pragma unroll
    for (int off = 8; off >= 1; off >>= 1) sq += __shfl_xor(sq, off);
    const float n = sqrtf(sq);
    const float v = a * (sq / (1.0f + sq) / (n + 1e-8f));
    if (mode == 0)      vsum[e] = v;
    else if (mode == 1) vsum[e] += v;
    else                out[e] = v;
}

// ------------------------------------- tier-3 fallback: fp32 VALU path
template<bool FIRST>
__global__ __launch_bounds__(1024, 4)
void caps_pass_f32(const float* __restrict__ x, const float* __restrict__ W,
                   const float* __restrict__ vsumg, float* __restrict__ sdst)
{
    __shared__ float wlds[2][8192];
    const int tid = threadIdx.x, lane = tid & 63;
    const int c = tid & 31, dh = (tid >> 5) & 1, w = tid >> 6;
    const int r0 = blockIdx.x * RB, b0 = w << 2;
    const int key = (c & 7) << 4;
    const int cb  = (c << 10) + (dh << 5);

    float sacc[4][8];
#pragma unroll
    for (int q = 0; q < 4; ++q)
#pragma unroll
        for (int k = 0; k < 8; ++k) sacc[q][k] = 0.0f;

    float vreg[4][8];
    if (!FIRST) {
#pragma unroll
        for (int q = 0; q < 4; ++q) {
            const float4* vp = (const float4*)(vsumg + ((((b0+q) << 5) + c) << 4) + (dh << 3));
            float4 a = vp[0], bq = vp[1];
            vreg[q][0]=a.x; vreg[q][1]=a.y; vreg[q][2]=a.z; vreg[q][3]=a.w;
            vreg[q][4]=bq.x; vreg[q][5]=bq.y; vreg[q][6]=bq.z; vreg[q][7]=bq.w;
        }
    }

    const int Dloc0 = (w << 11);
    const int lx0 = (lane << 4) ^ ((((w << 1))     & 7) << 4);
    const int lx1 = (lane << 4) ^ ((((w << 1) | 1) & 7) << 4);
    const int wu = __builtin_amdgcn_readfirstlane(w);
    const float* xw = x + (size_t)((wu << 2) * R_ + r0) * 16;

#define STAGE(buf, r)                                                              \
    do {                                                                           \
        const char* wr_ = (const char*)W + ((size_t)(r) << 15);                    \
        gload_lds16(wr_ + Dloc0        + lx0, (char*)wlds[buf] + Dloc0);           \
        gload_lds16(wr_ + Dloc0 + 1024 + lx1, (char*)wlds[buf] + Dloc0 + 1024);    \
    } while (0)

    STAGE(0, r0);
#pragma unroll 1
    for (int t = 0; t < RB; ++t) {
        const int cur = t & 1;
        if (t + 1 < RB) { STAGE(cur ^ 1, r0 + t + 1); asm volatile("s_waitcnt vmcnt(2)" ::: "memory"); }
        else            { asm volatile("s_waitcnt vmcnt(0)" ::: "memory"); }
        __builtin_amdgcn_s_barrier();
        __builtin_amdgcn_sched_barrier(0);

        const char* lb = (const char*)wlds[cur];
        float u[4][8];
#pragma unroll
        for (int q = 0; q < 4; ++q)
#pragma unroll
            for (int k = 0; k < 8; ++k) u[q][k] = 0.0f;

#pragma unroll
        for (int i = 0; i < 16; ++i) {
            const int A = (cb + (i << 6)) ^ key;
            float4 w0 = *(const float4*)(lb + A);
            float4 w1 = *(const float4*)(lb + (A ^ 16));
            float wv[8] = {w0.x, w0.y, w0.z, w0.w, w1.x, w1.y, w1.z, w1.w};
#pragma unroll
            for (int q = 0; q < 4; ++q) {
                const float xv = xw[(size_t)q * (R_ * 16) + t * 16 + i];
#pragma unroll
                for (int k = 0; k < 8; ++k) u[q][k] = fmaf(xv, wv[k], u[q][k]);
            }
        }

#pragma unroll
        for (int q = 0; q < 4; ++q) {
            float cij;
            if (FIRST) cij = 0.03125f;
            else {
                float th = 0.0f;
#pragma unroll
                for (int k = 0; k < 8; ++k) th = fmaf(u[q][k], vreg[q][k], th);
                th += __shfl_xor(th, 32);
                float m = th;
#pragma unroll
                for (int off = 16; off >= 1; off >>= 1) m = fmaxf(m, __shfl_xor(m, off));
                const float e = __expf(th - m);
                float ssum = e;
#pragma unroll
                for (int off = 16; off >= 1; off >>= 1) ssum += __shfl_xor(ssum, off);
                cij = e / ssum;
            }
#pragma unroll
            for (int k = 0; k < 8; ++k) sacc[q][k] = fmaf(cij, u[q][k], sacc[q][k]);
        }
        __builtin_amdgcn_s_barrier();
    }
#undef STAGE

#pragma unroll
    for (int q = 0; q < 4; ++q) {
        float* sp = sdst + ((((b0+q) << 5) + c) << 4) + (dh << 3);
#pragma unroll
        for (int k = 0; k < 8; ++k) atomicAdd(sp + k, sacc[q][k]);
    }
}

// ---------------------------------------------------------------- launcher
extern "C" void kernel_launch(void* const* d_in, const int* in_sizes, int n_in,
                              void* d_out, int out_size, void* d_ws, size_t ws_size,
                              hipStream_t stream)
{
    const float* x = (const float*)d_in[0];          // [64, 4608, 16]
    const float* W = (const float*)d_in[1];          // [4608, 32, 16, 16]
    float* out = (float*)d_out;                      // [64, 32, 16]

    const size_t WPB = (size_t)R_ * 16 * 64 * 8 * sizeof(_Float16);  // 75,497,472
    const size_t XAB = (size_t)R_ * 64 * 16 * sizeof(_Float16);      //  9,437,184
    const size_t SPB = (size_t)NBLK * SELEM * sizeof(float);         // 33,554,432
    const size_t S2B = (size_t)8 * SELEM * sizeof(float);
    const size_t VSB = (size_t)SELEM * sizeof(float);
    char* wsc = (char*)d_ws;
    const dim3 pgrid(NBLK, 2);

    if (ws_size >= WPB + XAB + SPB + S2B + VSB) {
        _Float16* wp  = (_Float16*)wsc;
        _Float16* xa  = (_Float16*)(wsc + WPB);
        float* s_part = (float*)(wsc + WPB + XAB);
        float* s2     = (float*)(wsc + WPB + XAB + SPB);
        float* vsumT  = (float*)(wsc + WPB + XAB + SPB + S2B);

        caps_prep<<<1152, 256, 0, stream>>>(x, xa);
        caps_wprep<<<R_ / 2, 512, 0, stream>>>(W, wp);

        caps_mfma<true ><<<pgrid, 512, 0, stream>>>(xa, wp, nullptr, s_part);
        caps_reduce1<<<dim3(128, 8), 256, 0, stream>>>(s_part, s2);
        caps_reduce2T<<<32, 64, 0, stream>>>(s2, vsumT, nullptr, 0);

        caps_mfma<false><<<pgrid, 512, 0, stream>>>(xa, wp, vsumT, s_part);
        caps_reduce1<<<dim3(128, 8), 256, 0, stream>>>(s_part, s2);
        caps_reduce2T<<<32, 64, 0, stream>>>(s2, vsumT, nullptr, 1);

        caps_mfma<false><<<pgrid, 512, 0, stream>>>(xa, wp, vsumT, s_part);
        caps_reduce1<<<dim3(128, 8), 256, 0, stream>>>(s_part, s2);
        caps_reduce2T<<<32, 64, 0, stream>>>(s2, vsumT, out, 2);
    } else {
        // tiny-ws fallback: fp32 VALU path (atomic accumulate, old layout)
        float* s    = (float*)wsc;
        float* vsum = s + SELEM;

        hipMemsetAsync(s, 0, VSB, stream);
        caps_pass_f32<true><<<NBLK, 1024, 0, stream>>>(x, W, nullptr, s);
        caps_reduce2<<<128, 256, 0, stream>>>(s, 1, vsum, nullptr, 0);

        hipMemsetAsync(s, 0, VSB, stream);
        caps_pass_f32<false><<<NBLK, 1024, 0, stream>>>(x, W, vsum, s);
        caps_reduce2<<<128, 256, 0, stream>>>(s, 1, vsum, nullptr, 1);

        hipMemsetAsync(s, 0, VSB, stream);
        caps_pass_f32<false><<<NBLK, 1024, 0, stream>>>(x, W, vsum, s);
        caps_reduce2<<<128, 256, 0, stream>>>(s, 1, nullptr, out, 2);
    }
}